// Round 1
// baseline (113.864 us; speedup 1.0000x reference)
//
#include <hip/hip_runtime.h>
#include <math.h>

#define BSZ 128
#define T   512
#define E   128
#define H   128
#define TPB 512   // 8 waves

// One block per batch row.
// loss contribution of row b: sum_{m=3}^{len-1} [ LSE_{k=m}^{len-1} cterm[k] - cterm[m] ]
// where cterm[k] = dot(enc[b,k,:], fc_w[H:]).  LSTM term cancels analytically.
__global__ __launch_bounds__(TPB) void dli_row_kernel(
    const float* __restrict__ enc,    // [B,T,E]
    const int*   __restrict__ mask,   // [B,T]
    const float* __restrict__ fc_w,   // [H+E]
    double*      __restrict__ accum)  // [2]: {loss_sum, pair_count}
{
    const int b    = blockIdx.x;
    const int t    = threadIdx.x;
    const int lane = t & 63;
    const int wid  = t >> 6;

    __shared__ float s_c[T];     // cterm
    __shared__ float s_e[T];     // exp / suffix sums
    __shared__ float s_red[8];
    __shared__ int   s_len;

    if (t == 0) s_len = 0;
    __syncthreads();

    // ---- length via ballot ----
    int mv = mask[b * T + t];
    unsigned long long bal = __ballot(mv != 0);
    if (lane == 0) atomicAdd(&s_len, __popcll(bal));

    // ---- cterm[k] = enc[b,k,:] . w_e  (wave-per-k, lane holds 2 elems) ----
    const float we0 = fc_w[H + 2 * lane];
    const float we1 = fc_w[H + 2 * lane + 1];
    const float* rowp = enc + (size_t)b * T * E;
    for (int k = wid; k < T; k += 8) {
        float2 v = *reinterpret_cast<const float2*>(rowp + k * E + 2 * lane);
        float p = v.x * we0 + v.y * we1;
        #pragma unroll
        for (int off = 32; off >= 1; off >>= 1)
            p += __shfl_xor(p, off);
        if (lane == 0) s_c[k] = p;
    }
    __syncthreads();
    const int len = s_len;

    // ---- row max over k in [3,len) ----
    float mval = (t >= 3 && t < len) ? s_c[t] : -INFINITY;
    #pragma unroll
    for (int off = 32; off >= 1; off >>= 1)
        mval = fmaxf(mval, __shfl_xor(mval, off));
    if (lane == 0) s_red[wid] = mval;
    __syncthreads();
    if (t == 0) {
        float m = s_red[0];
        #pragma unroll
        for (int i = 1; i < 8; i++) m = fmaxf(m, s_red[i]);
        s_red[0] = m;
    }
    __syncthreads();
    const float Mrow = s_red[0];

    // ---- exp terms ----
    s_e[t] = (t >= 3 && t < len) ? expf(s_c[t] - Mrow) : 0.0f;
    __syncthreads();

    // ---- suffix inclusive sum scan (Hillis-Steele), 9 steps ----
    for (int d = 1; d < T; d <<= 1) {
        float add = (t + d < T) ? s_e[t + d] : 0.0f;
        __syncthreads();
        s_e[t] += add;
        __syncthreads();
    }

    // ---- per-m loss terms + block reduce ----
    float term = 0.0f;
    if (t >= 3 && t < len)
        term = Mrow + logf(s_e[t]) - s_c[t];
    #pragma unroll
    for (int off = 32; off >= 1; off >>= 1)
        term += __shfl_xor(term, off);
    if (lane == 0) s_red[wid] = term;
    __syncthreads();
    if (t == 0) {
        float rs = 0.0f;
        #pragma unroll
        for (int i = 0; i < 8; i++) rs += s_red[i];
        int cnt = len - 3; if (cnt < 0) cnt = 0;
        atomicAdd(&accum[0], (double)rs);
        atomicAdd(&accum[1], (double)cnt);
    }
}

__global__ void dli_final(const double* __restrict__ accum,
                          float* __restrict__ out)
{
    out[0] = (float)(accum[0] / accum[1]);
}

extern "C" void kernel_launch(void* const* d_in, const int* in_sizes, int n_in,
                              void* d_out, int out_size, void* d_ws, size_t ws_size,
                              hipStream_t stream) {
    const float* enc  = (const float*)d_in[0];   // encoder_output [128,512,128] f32
    const int*   mask = (const int*)d_in[1];     // mask [128,512] i32
    const float* fc_w = (const float*)d_in[6];   // fc_w [1,256] f32
    // d_in[2..5] (LSTM weights) and d_in[7] (fc_b) cancel analytically.

    double* accum = (double*)d_ws;
    hipMemsetAsync(d_ws, 0, 2 * sizeof(double), stream);

    dli_row_kernel<<<BSZ, TPB, 0, stream>>>(enc, mask, fc_w, accum);
    dli_final<<<1, 1, 0, stream>>>(accum, (float*)d_out);
}

// Round 2
// 95.989 us; speedup vs baseline: 1.1862x; 1.1862x over previous
//
#include <hip/hip_runtime.h>
#include <math.h>

#define BSZ 128
#define T   512
#define E   128
#define H   128

// ---------------- Phase 1: cterm[b,k] = dot(enc[b,k,:], fc_w[H:]) ----------------
// 65536 rows total. Each half-wave (32 lanes x float4 = 128 floats) handles one row.
// Block = 256 threads = 4 waves = 8 rows; grid = 65536/8 = 8192 blocks.
// Rows with mask==0 are skipped (their cterm is never read by phase 2).
__global__ __launch_bounds__(256) void dli_dot_kernel(
    const float* __restrict__ enc,    // [B*T, E]
    const int*   __restrict__ mask,   // [B*T]
    const float* __restrict__ fc_w,   // [H+E]
    float*       __restrict__ cterm)  // [B*T]
{
    const int t    = threadIdx.x;
    const int lane = t & 63;
    const int wid  = t >> 6;
    const int sub  = lane >> 5;       // which row within the wave
    const int li   = lane & 31;       // lane within row
    const long row = (long)blockIdx.x * 8 + wid * 2 + sub;

    if (mask[row] == 0) return;       // prefix mask: k >= len, never used downstream

    const float4 w4 = *reinterpret_cast<const float4*>(fc_w + H + 4 * li);
    const float4 v  = *reinterpret_cast<const float4*>(enc + row * E + 4 * li);
    float p = v.x * w4.x + v.y * w4.y + v.z * w4.z + v.w * w4.w;
    #pragma unroll
    for (int off = 16; off >= 1; off >>= 1)
        p += __shfl_xor(p, off);      // xor<32 stays within the 32-lane row group
    if (li == 0) cterm[row] = p;
}

// ---------------- Phase 2: per-row suffix-LSE + masked mean ----------------
// loss contribution of row b: sum_{m=3}^{len-1} [ LSE_{k=m}^{len-1} cterm[k] - cterm[m] ]
// (the LSTM term and fc_b cancel analytically).
__global__ __launch_bounds__(T) void dli_scan_kernel(
    const float* __restrict__ cterm,  // [B*T]
    const int*   __restrict__ mask,   // [B*T]
    double*      __restrict__ accum)  // [2]: {loss_sum, pair_count}
{
    const int b    = blockIdx.x;
    const int t    = threadIdx.x;
    const int lane = t & 63;
    const int wid  = t >> 6;

    __shared__ float s_c[T];
    __shared__ float s_e[T];
    __shared__ float s_red[8];
    __shared__ int   s_len;

    if (t == 0) s_len = 0;
    __syncthreads();

    const int mv = mask[b * T + t];
    unsigned long long bal = __ballot(mv != 0);
    if (lane == 0) atomicAdd(&s_len, __popcll(bal));

    s_c[t] = mv ? cterm[b * T + t] : 0.0f;   // guard: masked entries are unwritten
    __syncthreads();
    const int len = s_len;

    // row max over k in [3,len)
    float mval = (t >= 3 && t < len) ? s_c[t] : -INFINITY;
    #pragma unroll
    for (int off = 32; off >= 1; off >>= 1)
        mval = fmaxf(mval, __shfl_xor(mval, off));
    if (lane == 0) s_red[wid] = mval;
    __syncthreads();
    if (t == 0) {
        float m = s_red[0];
        #pragma unroll
        for (int i = 1; i < 8; i++) m = fmaxf(m, s_red[i]);
        s_red[0] = m;
    }
    __syncthreads();
    const float Mrow = s_red[0];

    s_e[t] = (t >= 3 && t < len) ? expf(s_c[t] - Mrow) : 0.0f;
    __syncthreads();

    // suffix inclusive sum (Hillis-Steele), 9 steps
    for (int d = 1; d < T; d <<= 1) {
        float add = (t + d < T) ? s_e[t + d] : 0.0f;
        __syncthreads();
        s_e[t] += add;
        __syncthreads();
    }

    float term = 0.0f;
    if (t >= 3 && t < len)
        term = Mrow + logf(s_e[t]) - s_c[t];
    #pragma unroll
    for (int off = 32; off >= 1; off >>= 1)
        term += __shfl_xor(term, off);
    if (lane == 0) s_red[wid] = term;
    __syncthreads();
    if (t == 0) {
        float rs = 0.0f;
        #pragma unroll
        for (int i = 0; i < 8; i++) rs += s_red[i];
        int cnt = len - 3; if (cnt < 0) cnt = 0;
        atomicAdd(&accum[0], (double)rs);
        atomicAdd(&accum[1], (double)cnt);
    }
}

__global__ void dli_final(const double* __restrict__ accum,
                          float* __restrict__ out)
{
    out[0] = (float)(accum[0] / accum[1]);
}

extern "C" void kernel_launch(void* const* d_in, const int* in_sizes, int n_in,
                              void* d_out, int out_size, void* d_ws, size_t ws_size,
                              hipStream_t stream) {
    const float* enc  = (const float*)d_in[0];   // encoder_output [128,512,128] f32
    const int*   mask = (const int*)d_in[1];     // mask [128,512] i32
    const float* fc_w = (const float*)d_in[6];   // fc_w [1,256] f32
    // d_in[2..5] (LSTM weights) and d_in[7] (fc_b) cancel analytically.

    double* accum = (double*)d_ws;
    float*  cterm = (float*)((char*)d_ws + 16);
    hipMemsetAsync(d_ws, 0, 2 * sizeof(double), stream);

    dli_dot_kernel<<<(BSZ * T) / 8, 256, 0, stream>>>(enc, mask, fc_w, cterm);
    dli_scan_kernel<<<BSZ, T, 0, stream>>>(cterm, mask, accum);
    dli_final<<<1, 1, 0, stream>>>(accum, (float*)d_out);
}